// Round 20
// baseline (655.127 us; speedup 1.0000x reference)
//
#include <hip/hip_runtime.h>
#include <stdint.h>

#define B_ 2
#define T_ 2048
#define C_ 2048
#define F_ 8192
#define M_ 4096   // B_*T_
#define BC_ 4096  // B_*C_
#define CHB 16    // channels per WKV block
#define TCH 16    // time chunks per WKV block
#define LC2 128   // T_/TCH

typedef __attribute__((ext_vector_type(8))) __bf16 bf16x8;
typedef __attribute__((ext_vector_type(4))) float f32x4;

__device__ __forceinline__ unsigned short f2bf(float f) {
  union { float f; unsigned u; } v; v.f = f;
  unsigned r = v.u + 0x7fffu + ((v.u >> 16) & 1u);
  return (unsigned short)(r >> 16);
}
__device__ __forceinline__ float b2f(unsigned short h) {
  union { unsigned u; float f; } v; v.u = ((unsigned)h) << 16; return v.f;
}

__device__ __forceinline__ void gload16(const void* g, void* l) {
  __builtin_amdgcn_global_load_lds((__attribute__((address_space(1))) void*)g,
                                   (__attribute__((address_space(3))) void*)l,
                                   16, 0, 0);
}

// ---------- transpose + f32->bf16, vectorized uint writes ----------
__device__ __forceinline__ void transpose_tile(
    const float* __restrict__ W, unsigned short* __restrict__ out,
    int K, int N, int k0, int n0) {
  __shared__ unsigned short tile[32][66];
  const int tx = threadIdx.x & 31, ty = threadIdx.x >> 5;
#pragma unroll
  for (int i = 0; i < 8; ++i)
    tile[tx][ty + 8 * i] = f2bf(W[(size_t)(k0 + ty + 8 * i) * N + n0 + tx]);
  __syncthreads();
#pragma unroll
  for (int j = 0; j < 4; ++j) {
    const int nn = ty + 8 * j;
    const unsigned pk = *(const unsigned*)&tile[nn][2 * tx];
    *(unsigned*)&out[(size_t)(n0 + nn) * K + k0 + 2 * tx] = pk;
  }
}

__global__ __launch_bounds__(256) void k_transpose4(
    const float* __restrict__ W0, const float* __restrict__ W1,
    const float* __restrict__ W2, const float* __restrict__ W3,
    unsigned short* __restrict__ WT) {
  const float* W = (blockIdx.z == 0) ? W0 : (blockIdx.z == 1) ? W1
                   : (blockIdx.z == 2) ? W2 : W3;
  unsigned short* out = WT + (size_t)blockIdx.z * C_ * C_;
  transpose_tile(W, out, C_, C_, blockIdx.x * 64, blockIdx.y * 32);
}

__global__ __launch_bounds__(256) void k_transpose1(
    const float* __restrict__ W, unsigned short* __restrict__ WT, int K, int N) {
  transpose_tile(W, WT, K, N, blockIdx.x * 64, blockIdx.y * 32);
}

// ---------- LayerNorm over C=2048 (f32 in, bf16 out + f32 last-row out) ----------
__global__ __launch_bounds__(256) void k_layernorm(
    const float* __restrict__ x, const float* __restrict__ g,
    const float* __restrict__ beta, unsigned short* __restrict__ y,
    float* __restrict__ last_out) {
  const int row = blockIdx.x;
  const int t = row & (T_ - 1);
  const int bi = row >> 11;
  const float* xr = x + (size_t)row * C_;
  const int base = threadIdx.x * 8;
  float lv[8];
  {
    float4 a = *(const float4*)(xr + base);
    float4 b = *(const float4*)(xr + base + 4);
    lv[0]=a.x; lv[1]=a.y; lv[2]=a.z; lv[3]=a.w; lv[4]=b.x; lv[5]=b.y; lv[6]=b.z; lv[7]=b.w;
  }
  float s = 0.f, q = 0.f;
#pragma unroll
  for (int j = 0; j < 8; ++j) { s += lv[j]; q += lv[j] * lv[j]; }
#pragma unroll
  for (int o = 32; o > 0; o >>= 1) { s += __shfl_down(s, o); q += __shfl_down(q, o); }
  __shared__ float rs[4], rq[4];
  if ((threadIdx.x & 63) == 0) { rs[threadIdx.x >> 6] = s; rq[threadIdx.x >> 6] = q; }
  __syncthreads();
  s = rs[0] + rs[1] + rs[2] + rs[3];
  q = rq[0] + rq[1] + rq[2] + rq[3];
  const float mean = s * (1.f / C_);
  const float var = q * (1.f / C_) - mean * mean;
  const float inv = 1.f / sqrtf(var + 1e-5f);
  float ov[8];
  unsigned short o8[8];
#pragma unroll
  for (int j = 0; j < 8; ++j) {
    ov[j] = (lv[j] - mean) * inv * g[base + j] + beta[base + j];
    o8[j] = f2bf(ov[j]);
  }
  *(uint4*)(y + (size_t)row * C_ + base) = *(uint4*)o8;
  if (last_out != nullptr && t == T_ - 1) {
    float* lp = last_out + (size_t)bi * C_ + base;
    *(float4*)lp = make_float4(ov[0], ov[1], ov[2], ov[3]);
    *(float4*)(lp + 4) = make_float4(ov[4], ov[5], ov[6], ov[7]);
  }
}

// ---------- token-shift mix (attention: 3 outputs), bf16 in/out ----------
__global__ __launch_bounds__(256) void k_mix3(
    const unsigned short* __restrict__ x1, const float* __restrict__ shift,
    const float* __restrict__ tmk, const float* __restrict__ tmv,
    const float* __restrict__ tmr,
    unsigned short* __restrict__ xk, unsigned short* __restrict__ xv,
    unsigned short* __restrict__ xr) {
  const int row = blockIdx.x;
  const int t = row & (T_ - 1);
  const int bi = row >> 11;
  const int c0 = threadIdx.x * 8;
  const size_t o = (size_t)row * C_ + c0;
  unsigned short cur8[8];
  *(uint4*)cur8 = *(const uint4*)(x1 + o);
  float pv[8];
  if (t == 0) {
    const float* sp = shift + (size_t)bi * C_ + c0;
#pragma unroll
    for (int j = 0; j < 8; ++j) pv[j] = sp[j];
  } else {
    unsigned short p8[8];
    *(uint4*)p8 = *(const uint4*)(x1 + o - C_);
#pragma unroll
    for (int j = 0; j < 8; ++j) pv[j] = b2f(p8[j]);
  }
  unsigned short ok[8], ov[8], orr[8];
#pragma unroll
  for (int j = 0; j < 8; ++j) {
    const float a = b2f(cur8[j]), p = pv[j];
    const float mk = tmk[c0 + j], mv = tmv[c0 + j], mr = tmr[c0 + j];
    ok[j]  = f2bf(a * mk + p * (1.f - mk));
    ov[j]  = f2bf(a * mv + p * (1.f - mv));
    orr[j] = f2bf(a * mr + p * (1.f - mr));
  }
  *(uint4*)(xk + o) = *(uint4*)ok;
  *(uint4*)(xv + o) = *(uint4*)ov;
  *(uint4*)(xr + o) = *(uint4*)orr;
}

// ---------- token-shift mix (ffn: 2 outputs) ----------
__global__ __launch_bounds__(256) void k_mix2(
    const unsigned short* __restrict__ x2, const float* __restrict__ shift,
    const float* __restrict__ fmk, const float* __restrict__ fmr,
    unsigned short* __restrict__ xk2, unsigned short* __restrict__ xr2) {
  const int row = blockIdx.x;
  const int t = row & (T_ - 1);
  const int bi = row >> 11;
  const int c0 = threadIdx.x * 8;
  const size_t o = (size_t)row * C_ + c0;
  unsigned short cur8[8];
  *(uint4*)cur8 = *(const uint4*)(x2 + o);
  float pv[8];
  if (t == 0) {
    const float* sp = shift + (size_t)bi * C_ + c0;
#pragma unroll
    for (int j = 0; j < 8; ++j) pv[j] = sp[j];
  } else {
    unsigned short p8[8];
    *(uint4*)p8 = *(const uint4*)(x2 + o - C_);
#pragma unroll
    for (int j = 0; j < 8; ++j) pv[j] = b2f(p8[j]);
  }
  unsigned short ok[8], orr[8];
#pragma unroll
  for (int j = 0; j < 8; ++j) {
    const float a = b2f(cur8[j]), p = pv[j];
    const float mk = fmk[c0 + j], mr = fmr[c0 + j];
    ok[j]  = f2bf(a * mk + p * (1.f - mk));
    orr[j] = f2bf(a * mr + p * (1.f - mr));
  }
  *(uint4*)(xk2 + o) = *(uint4*)ok;
  *(uint4*)(xr2 + o) = *(uint4*)orr;
}

// ---------- WKV scan fused with sigmoid(r)*y; k/v/r arrive as bf16 partial pairs --
__global__ __launch_bounds__(256) void k_wkv_sry(
    const unsigned short* __restrict__ k0p, const unsigned short* __restrict__ k1p,
    const unsigned short* __restrict__ v0p, const unsigned short* __restrict__ v1p,
    const unsigned short* __restrict__ r0p, const unsigned short* __restrict__ r1p,
    const float* __restrict__ td, const float* __restrict__ tf,
    const float* __restrict__ st, unsigned short* __restrict__ sry,
    float* __restrict__ out_state) {
  __shared__ float sA[TCH][CHB], sB[TCH][CHB], sP[TCH][CHB];
  const int blk = blockIdx.x;
  const int bi = blk >> 7;
  const int tx = threadIdx.x & 15;
  const int ty = threadIdx.x >> 4;
  const int c = ((blk & 127) * CHB) + tx;
  const float w = -expf(td[c]);
  const float u = tf[c];
  const size_t base = (size_t)bi * T_ * C_ + (size_t)ty * LC2 * C_ + c;
  const unsigned short* ka = k0p + base;
  const unsigned short* kb = k1p + base;
  const unsigned short* va = v0p + base;
  const unsigned short* vb = v1p + base;
  float aa = 0.f, bb = 0.f, pp = -1e38f;
#pragma unroll 8
  for (int i = 0; i < LC2; ++i) {
    const float kt = b2f(ka[(size_t)i * C_]) + b2f(kb[(size_t)i * C_]);
    const float vt = b2f(va[(size_t)i * C_]) + b2f(vb[(size_t)i * C_]);
    const float ww2 = pp + w;
    const float p2 = fmaxf(ww2, kt);
    const float e1b = expf(ww2 - p2), e2b = expf(kt - p2);
    aa = e1b * aa + e2b * vt;
    bb = e1b * bb + e2b;
    pp = p2;
  }
  sA[ty][tx] = aa; sB[ty][tx] = bb; sP[ty][tx] = pp;
  __syncthreads();
  if (ty == 0) {
    const float* s0 = st + (size_t)bi * 3 * C_;
    float ca = s0[c], cb = s0[C_ + c], cp = s0[2 * C_ + c];
    const float wL = w * (float)LC2;
#pragma unroll
    for (int j = 0; j < TCH; ++j) {
      const float a2 = sA[j][tx], b2 = sB[j][tx], p2 = sP[j][tx];
      sA[j][tx] = ca; sB[j][tx] = cb; sP[j][tx] = cp;   // exclusive start
      const float pd = cp + wL;
      const float pm = fmaxf(pd, p2);
      const float e1 = expf(pd - pm), e2 = expf(p2 - pm);
      ca = e1 * ca + e2 * a2;
      cb = e1 * cb + e2 * b2;
      cp = pm;
    }
  }
  __syncthreads();
  aa = sA[ty][tx]; bb = sB[ty][tx]; pp = sP[ty][tx];
  const unsigned short* ra = r0p + base;
  const unsigned short* rb = r1p + base;
  unsigned short* sp2 = sry + base;
#pragma unroll 4
  for (int i = 0; i < LC2; ++i) {
    const float kt = b2f(ka[(size_t)i * C_]) + b2f(kb[(size_t)i * C_]);
    const float vt = b2f(va[(size_t)i * C_]) + b2f(vb[(size_t)i * C_]);
    const float ww = u + kt;
    const float p = fmaxf(pp, ww);
    const float e1 = expf(pp - p), e2 = expf(ww - p);
    const float yv = (e1 * aa + e2 * vt) / (e1 * bb + e2);
    const float rv = b2f(ra[(size_t)i * C_]) + b2f(rb[(size_t)i * C_]);
    const float sg = 1.f / (1.f + expf(-rv));
    sp2[(size_t)i * C_] = f2bf(sg * yv);
    const float ww2 = pp + w;
    const float p2 = fmaxf(ww2, kt);
    const float e1b = expf(ww2 - p2), e2b = expf(kt - p2);
    aa = e1b * aa + e2b * vt;
    bb = e1b * bb + e2b;
    pp = p2;
  }
  if (ty == TCH - 1) {
    float* ob = out_state + (size_t)bi * 3 * C_;
    ob[c] = aa; ob[C_ + c] = bb; ob[2 * C_ + c] = pp;
  }
}

// ---------- bf16 MFMA GEMM: 128x256 tile, BK=64, 8 waves, single-barrier tiles --
// EPI 0: f32; 1: bf16(relu^2); 2: f32(aux1+acc); 3: f32(aux1+sig(acc)*aux2f32);
// 4: bf16 plain; 5: f32(aux1 + sig(acc)*(b2f(aux2bf)+b2f(aux3bf)))
template <int EPI, int SWZ>
__global__ __launch_bounds__(512, 1) void k_gemm8(
    const unsigned short* __restrict__ A, const unsigned short* __restrict__ BT,
    int K, int Nn, void* __restrict__ out,
    const float* __restrict__ aux1, const void* __restrict__ aux2,
    const void* __restrict__ aux3) {
  __shared__ unsigned short lds[73728];
  const int tid = threadIdx.x;
  const int lane = tid & 63;
  const int wid = tid >> 6;
  int mBase, nBase;
  if (SWZ) {
    const int gx = gridDim.x, gy = gridDim.y;
    const int wg = blockIdx.y * gx + blockIdx.x;
    const int per = (gx * gy) >> 3;
    const int p = 31 - __clz(per);
    const int nr = 1 << ((p - 1) >> 1);
    const int mr = per / nr;
    if ((gx % nr) == 0 && (gy % mr) == 0) {
      const int gxr = gx / nr;
      const int xcd = wg & 7, idx = wg >> 3;
      const int rr = xcd / gxr, rc = xcd % gxr;
      mBase = (rr * mr + idx / nr) * 128;
      nBase = (rc * nr + idx % nr) * 256;
    } else {
      int w2 = (wg & 7) * per + (wg >> 3);
      mBase = (w2 / gx) * 128;
      nBase = (w2 % gx) * 256;
    }
  } else {
    mBase = blockIdx.y * 128;
    nBase = blockIdx.x * 256;
  }
  const int wr = (wid >> 2) * 64;
  const int wc = (wid & 3) * 64;
  const int r16 = lane & 15, kq = lane >> 4;
  const int lrow = lane >> 3;
  const int lslot = (lane & 7) ^ lrow;
  const int xsw = r16 & 7;
  f32x4 acc[4][4] = {};

  const unsigned short* gA0 = A  + (size_t)(mBase + 0   + wid * 8 + lrow) * K + lslot * 8;
  const unsigned short* gA1 = A  + (size_t)(mBase + 64  + wid * 8 + lrow) * K + lslot * 8;
  const unsigned short* gB0 = BT + (size_t)(nBase + 0   + wid * 8 + lrow) * K + lslot * 8;
  const unsigned short* gB1 = BT + (size_t)(nBase + 64  + wid * 8 + lrow) * K + lslot * 8;
  const unsigned short* gB2 = BT + (size_t)(nBase + 128 + wid * 8 + lrow) * K + lslot * 8;
  const unsigned short* gB3 = BT + (size_t)(nBase + 192 + wid * 8 + lrow) * K + lslot * 8;
  const int wof = wid * 512;
  int aoff[4][2], boff[4][2];
#pragma unroll
  for (int m = 0; m < 4; ++m)
#pragma unroll
    for (int s = 0; s < 2; ++s)
      aoff[m][s] = (wr + m * 16 + r16) * 64 + (((s * 4 + kq) ^ xsw) * 8);
#pragma unroll
  for (int n = 0; n < 4; ++n)
#pragma unroll
    for (int s = 0; s < 2; ++s)
      boff[n][s] = 8192 + (wc + n * 16 + r16) * 64 + (((s * 4 + kq) ^ xsw) * 8);

  const int nt = K >> 6;
  gload16(gA0, &lds[0 + wof]);
  gload16(gA1, &lds[4096 + wof]);
  gload16(gB0, &lds[8192 + wof]);
  gload16(gB1, &lds[12288 + wof]);
  gload16(gB2, &lds[16384 + wof]);
  gload16(gB3, &lds[20480 + wof]);
  gload16(gA0 + 64, &lds[24576 + 0 + wof]);
  gload16(gA1 + 64, &lds[24576 + 4096 + wof]);
  gload16(gB0 + 64, &lds[24576 + 8192 + wof]);
  gload16(gB1 + 64, &lds[24576 + 12288 + wof]);
  gload16(gB2 + 64, &lds[24576 + 16384 + wof]);
  gload16(gB3 + 64, &lds[24576 + 20480 + wof]);
  asm volatile("s_waitcnt vmcnt(6)" ::: "memory");
  asm volatile("s_barrier" ::: "memory");

  int cb = 0;
  for (int t = 0; t < nt; ++t) {
    const int nb = (cb >= 1) ? cb - 1 : 2;
    const int ca = cb * 24576;
    const int nba = nb * 24576;
    const int kb2 = (t + 2) << 6;
    const bool pf = (t + 2) < nt;
    if (pf) {
      gload16(gA0 + kb2, &lds[nba + 0 + wof]);
      gload16(gA1 + kb2, &lds[nba + 4096 + wof]);
      gload16(gB0 + kb2, &lds[nba + 8192 + wof]);
      gload16(gB1 + kb2, &lds[nba + 12288 + wof]);
      gload16(gB2 + kb2, &lds[nba + 16384 + wof]);
      gload16(gB3 + kb2, &lds[nba + 20480 + wof]);
    }
    bf16x8 af[4][2], bq[4][2];
#pragma unroll
    for (int m = 0; m < 4; ++m)
#pragma unroll
      for (int s = 0; s < 2; ++s)
        af[m][s] = *(const bf16x8*)&lds[ca + aoff[m][s]];
#pragma unroll
    for (int n = 0; n < 4; ++n)
#pragma unroll
      for (int s = 0; s < 2; ++s)
        bq[n][s] = *(const bf16x8*)&lds[ca + boff[n][s]];
    __builtin_amdgcn_s_setprio(1);
#pragma unroll
    for (int m = 0; m < 4; ++m)
#pragma unroll
      for (int n = 0; n < 4; ++n)
#pragma unroll
        for (int s = 0; s < 2; ++s)
          acc[m][n] = __builtin_amdgcn_mfma_f32_16x16x32_bf16(
              af[m][s], bq[n][s], acc[m][n], 0, 0, 0);
    __builtin_amdgcn_s_setprio(0);
    if (pf) {
      asm volatile("s_waitcnt vmcnt(6)" ::: "memory");
    } else if (t + 1 < nt) {
      asm volatile("s_waitcnt vmcnt(0)" ::: "memory");
    }
    asm volatile("s_barrier" ::: "memory");
    cb = (cb == 2) ? 0 : cb + 1;
  }

  const int c0 = kq * 4;
#pragma unroll
  for (int m = 0; m < 4; ++m) {
#pragma unroll
    for (int n = 0; n < 4; ++n) {
      const int col = nBase + wc + n * 16 + r16;
#pragma unroll
      for (int e = 0; e < 4; ++e) {
        const int rowg = mBase + wr + m * 16 + c0 + e;
        const size_t idx = (size_t)rowg * Nn + col;
        const float va = acc[m][n][e];
        if (EPI == 0) {
          ((float*)out)[idx] = va;
        } else if (EPI == 1) {
          const float t = va > 0.f ? va : 0.f;
          ((unsigned short*)out)[idx] = f2bf(t * t);
        } else if (EPI == 2) {
          ((float*)out)[idx] = aux1[idx] + va;
        } else if (EPI == 3) {
          const float s = 1.f / (1.f + expf(-va));
          ((float*)out)[idx] = aux1[idx] + s * ((const float*)aux2)[idx];
        } else if (EPI == 5) {
          const float s = 1.f / (1.f + expf(-va));
          const float kvv = b2f(((const unsigned short*)aux2)[idx]) +
                            b2f(((const unsigned short*)aux3)[idx]);
          ((float*)out)[idx] = aux1[idx] + s * kvv;
        } else {
          ((unsigned short*)out)[idx] = f2bf(va);
        }
      }
    }
  }
}

// ---------- shared 256x256 GEMM core (round-17 pipeline): computes acc ----------
__device__ __forceinline__ void gemm256_core(
    const unsigned short* __restrict__ A, const unsigned short* __restrict__ BT,
    int K, int Klen, int Koff, int mBase, int nBase,
    unsigned short* lds, f32x4 (&acc)[8][4]) {
  const int lane = threadIdx.x & 63;
  const int wid = threadIdx.x >> 6;
  const int wr = (wid >> 2) * 128;
  const int wc = (wid & 3) * 64;
  const int r16 = lane & 15, kq = lane >> 4;
  const int lrow = lane >> 3;
  const int lslot = (lane & 7) ^ lrow;
  const int xsw = r16 & 7;
  const unsigned short* gA[4];
  const unsigned short* gB[4];
#pragma unroll
  for (int j = 0; j < 4; ++j) {
    gA[j] = A  + (size_t)(mBase + j * 64 + wid * 8 + lrow) * K + Koff + lslot * 8;
    gB[j] = BT + (size_t)(nBase + j * 64 + wid * 8 + lrow) * K + Koff + lslot * 8;
  }
  const int wof = wid * 512;
  const int nt = Klen >> 6;
#pragma unroll
  for (int j = 0; j < 4; ++j) {
    gload16(gA[j], &lds[j * 4096 + wof]);
    gload16(gB[j], &lds[16384 + j * 4096 + wof]);
  }
  asm volatile("s_waitcnt vmcnt(0)" ::: "memory");
  asm volatile("s_barrier" ::: "memory");

  for (int t = 0; t < nt; ++t) {
    const int ca = (t & 1) * 32768;
    const int nba = ((t + 1) & 1) * 32768;
    const int kb1 = (t + 1) << 6;
    const bool pf = (t + 1) < nt;
    if (pf) {
#pragma unroll
      for (int j = 0; j < 4; ++j) {
        gload16(gA[j] + kb1, &lds[nba + j * 4096 + wof]);
        gload16(gB[j] + kb1, &lds[nba + 16384 + j * 4096 + wof]);
      }
    }
    bf16x8 bq[4][2];
#pragma unroll
    for (int n = 0; n < 4; ++n)
#pragma unroll
      for (int s = 0; s < 2; ++s)
        bq[n][s] = *(const bf16x8*)&lds[ca + 16384 + (wc + n * 16 + r16) * 64 +
                                        (((s * 4 + kq) ^ xsw) * 8)];
#pragma unroll
    for (int qm = 0; qm < 2; ++qm) {
      bf16x8 af[4][2];
#pragma unroll
      for (int m = 0; m < 4; ++m)
#pragma unroll
        for (int s = 0; s < 2; ++s)
          af[m][s] = *(const bf16x8*)&lds[ca + (wr + (qm * 4 + m) * 16 + r16) * 64 +
                                          (((s * 4 + kq) ^ xsw) * 8)];
      __builtin_amdgcn_s_setprio(1);
#pragma unroll
      for (int m = 0; m < 4; ++m)
#pragma unroll
        for (int n = 0; n < 4; ++n)
#pragma unroll
          for (int s = 0; s < 2; ++s)
            acc[qm * 4 + m][n] = __builtin_amdgcn_mfma_f32_16x16x32_bf16(
                af[m][s], bq[n][s], acc[qm * 4 + m][n], 0, 0, 0);
      __builtin_amdgcn_s_setprio(0);
    }
    if (pf) asm volatile("s_waitcnt vmcnt(0)" ::: "memory");
    asm volatile("s_barrier" ::: "memory");
  }
}

__device__ __forceinline__ void swz256(int gx, int gy, int& mBase, int& nBase) {
  const int wg = blockIdx.y * gx + blockIdx.x;
  const int per = (gx * gy) >> 3;
  const int p = 31 - __clz(per);
  const int nr = 1 << (p >> 1);
  const int mr = per / nr;
  if ((gx % nr) == 0 && (gy % mr) == 0) {
    const int gxr = gx / nr;
    const int xcd = wg & 7, idx = wg >> 3;
    const int rr = xcd / gxr, rc = xcd % gxr;
    mBase = (rr * mr + idx / nr) * 256;
    nBase = (rc * nr + idx % nr) * 256;
  } else {
    int w2 = (wg & 7) * per + (wg >> 3);
    mBase = (w2 / gx) * 256;
    nBase = (w2 % gx) * 256;
  }
}

// ---------- 256x256 GEMM (Fk / split-K kv): EPI 1 bf16(relu^2), 4 bf16 ----------
template <int EPI>
__global__ __launch_bounds__(512, 1) void k_gemm256(
    const unsigned short* __restrict__ A, const unsigned short* __restrict__ BT,
    int K, int Klen, int Nn, void* __restrict__ out, size_t outStride) {
  __shared__ unsigned short lds[65536];
  int mBase, nBase;
  swz256(gridDim.x, gridDim.y, mBase, nBase);
  void* outz = (char*)out + (size_t)blockIdx.z * outStride;
  f32x4 acc[8][4] = {};
  gemm256_core(A, BT, K, Klen, blockIdx.z * Klen, mBase, nBase, lds, acc);
  const int lane = threadIdx.x & 63;
  const int wid = threadIdx.x >> 6;
  const int wr = (wid >> 2) * 128, wc = (wid & 3) * 64;
  const int r16 = lane & 15, kq = lane >> 4;
  const int c0 = kq * 4;
#pragma unroll
  for (int m = 0; m < 8; ++m) {
#pragma unroll
    for (int n = 0; n < 4; ++n) {
      const int col = nBase + wc + n * 16 + r16;
#pragma unroll
      for (int e = 0; e < 4; ++e) {
        const int rowg = mBase + wr + m * 16 + c0 + e;
        const size_t idx = (size_t)rowg * Nn + col;
        const float va = acc[m][n][e];
        if (EPI == 1) {
          const float t = va > 0.f ? va : 0.f;
          ((unsigned short*)outz)[idx] = f2bf(t * t);
        } else {
          ((unsigned short*)outz)[idx] = f2bf(va);
        }
      }
    }
  }
}

// ---------- batched split-K k/v/r: grid (8,16,6), z -> (gemm, K-half) ----------
// 768 WGs = exactly 3 full 256-block passes (tail-free). bf16 partial outputs.
__global__ __launch_bounds__(512, 1) void k_gemm_kvr6(
    const unsigned short* __restrict__ xk, const unsigned short* __restrict__ xv,
    const unsigned short* __restrict__ xr,
    const unsigned short* __restrict__ sWk, const unsigned short* __restrict__ sWv,
    const unsigned short* __restrict__ sWr,
    unsigned short* __restrict__ k0, unsigned short* __restrict__ k1,
    unsigned short* __restrict__ v0, unsigned short* __restrict__ v1,
    unsigned short* __restrict__ r0, unsigned short* __restrict__ r1) {
  __shared__ unsigned short lds[65536];
  const int g = blockIdx.z >> 1, h = blockIdx.z & 1;
  const unsigned short* A  = (g == 0) ? xk  : (g == 1) ? xv  : xr;
  const unsigned short* BT = (g == 0) ? sWk : (g == 1) ? sWv : sWr;
  unsigned short* out = (g == 0) ? (h ? k1 : k0)
                      : (g == 1) ? (h ? v1 : v0) : (h ? r1 : r0);
  int mBase, nBase;
  swz256(gridDim.x, gridDim.y, mBase, nBase);
  f32x4 acc[8][4] = {};
  gemm256_core(A, BT, C_, C_ / 2, h * (C_ / 2), mBase, nBase, lds, acc);
  const int lane = threadIdx.x & 63;
  const int wid = threadIdx.x >> 6;
  const int wr = (wid >> 2) * 128, wc = (wid & 3) * 64;
  const int r16 = lane & 15, kq = lane >> 4;
  const int c0 = kq * 4;
#pragma unroll
  for (int m = 0; m < 8; ++m) {
#pragma unroll
    for (int n = 0; n < 4; ++n) {
      const int col = nBase + wc + n * 16 + r16;
#pragma unroll
      for (int e = 0; e < 4; ++e) {
        const int rowg = mBase + wr + m * 16 + c0 + e;
        out[(size_t)rowg * C_ + col] = f2bf(acc[m][n][e]);
      }
    }
  }
}

extern "C" void kernel_launch(void* const* d_in, const int* in_sizes, int n_in,
                              void* d_out, int out_size, void* d_ws, size_t ws_size,
                              hipStream_t stream) {
  const float* x          = (const float*)d_in[0];
  const float* att_shift  = (const float*)d_in[1];
  const float* wkv_state  = (const float*)d_in[2];
  const float* ffn_shift  = (const float*)d_in[3];
  const float* ln1_g = (const float*)d_in[4];
  const float* ln1_b = (const float*)d_in[5];
  const float* ln2_g = (const float*)d_in[6];
  const float* ln2_b = (const float*)d_in[7];
  const float* tmk = (const float*)d_in[8];
  const float* tmv = (const float*)d_in[9];
  const float* tmr = (const float*)d_in[10];
  const float* time_decay = (const float*)d_in[11];
  const float* time_first = (const float*)d_in[12];
  const float* Wk = (const float*)d_in[13];
  const float* Wv = (const float*)d_in[14];
  const float* Wr = (const float*)d_in[15];
  const float* Wo = (const float*)d_in[16];
  const float* fmk = (const float*)d_in[17];
  const float* fmr = (const float*)d_in[18];
  const float* Fk = (const float*)d_in[19];
  const float* Fr = (const float*)d_in[20];
  const float* Fv = (const float*)d_in[21];

  // ---- 176 MiB workspace, strictly sequential reuse, zero in-flight overlap ----
  const size_t MB = 1ull << 20;
  char* ws = (char*)d_ws;
  if (ws_size < 176 * MB) return;

  unsigned short* Wslot = (unsigned short*)(ws);             //   0.. 32 weight slots
  unsigned short* k0    = (unsigned short*)(ws + 32 * MB);   //  32.. 48 k partial 0
  unsigned short* k1    = (unsigned short*)(ws + 48 * MB);   //  48.. 64 k partial 1
  unsigned short* v0    = (unsigned short*)(ws + 64 * MB);   //  64.. 80 v partial 0
  unsigned short* v1    = (unsigned short*)(ws + 80 * MB);   //  80.. 96 v partial 1
  float*          yBuf  = (float*)(ws + 96 * MB);            //  96..128 xr|r1 -> x_att f32
  unsigned short* h1    = (unsigned short*)(ws + 128 * MB);  // 128..144 x1 -> r0 -> x2
  unsigned short* h2    = (unsigned short*)(ws + 144 * MB);  // 144..160 xk -> sry -> xk2
  unsigned short* h3    = (unsigned short*)(ws + 160 * MB);  // 160..176 xv -> xr2
  unsigned short* xrB   = (unsigned short*)yBuf;             // xr bf16 (96..112)
  unsigned short* r1    = (unsigned short*)(ws + 112 * MB);  // r partial 1 (112..128)
  unsigned short* r0    = h1;                                // r partial 0 (128..144)
  unsigned short* kf    = (unsigned short*)(ws + 32 * MB);   // 64 MiB: 32..96 (k,v dead)
  unsigned short* kvp   = (unsigned short*)h1;               // 2x16 MiB bf16 partials
  // 4 transposed C_xC_ weight slots inside Wslot (8 MiB each)
  unsigned short* sWr = Wslot + 0 * (size_t)C_ * C_;
  unsigned short* sWk = Wslot + 1 * (size_t)C_ * C_;
  unsigned short* sWv = Wslot + 2 * (size_t)C_ * C_;
  unsigned short* sWo = Wslot + 3 * (size_t)C_ * C_;

  // ---- f32 outputs, concatenated in reference return order ----
  float* outb    = (float*)d_out;
  float* x1_last = outb + (size_t)M_ * C_;        // [B,C]
  float* wkv_out = x1_last + (size_t)B_ * C_;     // [B,3,C]
  float* x2_last = wkv_out + (size_t)B_ * 3 * C_; // [B,C]

  const dim3 gC8(C_ / 256, M_ / 128);       // 8 x 32 = 256 WGs
  const dim3 gF256(F_ / 256, M_ / 256);     // 32 x 16 = 512 WGs
  const dim3 gKV(C_ / 256, M_ / 256, 2);    // split-K kv
  const dim3 gKVR(C_ / 256, M_ / 256, 6);   // split-K k/v/r: 768 WGs = 3 passes

  // ---- attention path ----
  k_transpose4<<<dim3(C_ / 64, C_ / 32, 4), 256, 0, stream>>>(Wr, Wk, Wv, Wo, Wslot);
  k_layernorm<<<M_, 256, 0, stream>>>(x, ln1_g, ln1_b, h1, x1_last);           // x1 -> h1
  k_mix3<<<M_, 256, 0, stream>>>(h1, att_shift, tmk, tmv, tmr, h2, h3, xrB);   // xk,xv,xr
  k_gemm_kvr6<<<gKVR, 512, 0, stream>>>(h2, h3, xrB, sWk, sWv, sWr,
                                        k0, k1, v0, v1, r0, r1);               // partials
  k_wkv_sry<<<dim3(BC_ / CHB), 256, 0, stream>>>(k0, k1, v0, v1, r0, r1,
                                                 time_decay, time_first,
                                                 wkv_state, h2, wkv_out);      // sry -> h2
  k_gemm8<2,1><<<gC8, 512, 0, stream>>>(h2, sWo, C_, C_, yBuf, x, nullptr, nullptr); // x_att

  // ---- ffn path ----
  k_layernorm<<<M_, 256, 0, stream>>>(yBuf, ln2_g, ln2_b, h1, x2_last);         // x2 -> h1
  k_mix2<<<M_, 256, 0, stream>>>(h1, ffn_shift, fmk, fmr, h2, h3);              // xk2,xr2
  k_transpose1<<<dim3(C_ / 64, F_ / 32), 256, 0, stream>>>(Fk, Wslot, C_, F_);
  k_gemm256<1><<<gF256, 512, 0, stream>>>(h2, Wslot, C_, C_, F_, kf, 0);        // kf bf16
  k_transpose1<<<dim3(F_ / 64, C_ / 32), 256, 0, stream>>>(Fv, Wslot, F_, C_);
  k_gemm256<4><<<gKV, 512, 0, stream>>>(kf, Wslot, F_, F_ / 2, C_, kvp, 16 * MB); // kv partials
  k_transpose1<<<dim3(C_ / 64, C_ / 32), 256, 0, stream>>>(Fr, Wslot, C_, C_);
  k_gemm8<5,1><<<gC8, 512, 0, stream>>>(h3, Wslot, C_, C_, d_out, yBuf,
                                        kvp, kvp + 8 * (size_t)MB);             // final f32
}

// Round 21
// 618.269 us; speedup vs baseline: 1.0596x; 1.0596x over previous
//
#include <hip/hip_runtime.h>
#include <stdint.h>

#define B_ 2
#define T_ 2048
#define C_ 2048
#define F_ 8192
#define M_ 4096   // B_*T_
#define BC_ 4096  // B_*C_
#define CHB 16    // channels per WKV block
#define TCH 16    // time chunks per WKV block
#define LC2 128   // T_/TCH

typedef __attribute__((ext_vector_type(8))) __bf16 bf16x8;
typedef __attribute__((ext_vector_type(4))) float f32x4;

__device__ __forceinline__ unsigned short f2bf(float f) {
  union { float f; unsigned u; } v; v.f = f;
  unsigned r = v.u + 0x7fffu + ((v.u >> 16) & 1u);
  return (unsigned short)(r >> 16);
}
__device__ __forceinline__ float b2f(unsigned short h) {
  union { unsigned u; float f; } v; v.u = ((unsigned)h) << 16; return v.f;
}

__device__ __forceinline__ void gload16(const void* g, void* l) {
  __builtin_amdgcn_global_load_lds((__attribute__((address_space(1))) void*)g,
                                   (__attribute__((address_space(3))) void*)l,
                                   16, 0, 0);
}

// ---------- transpose + f32->bf16, vectorized uint writes ----------
__device__ __forceinline__ void transpose_tile(
    const float* __restrict__ W, unsigned short* __restrict__ out,
    int K, int N, int k0, int n0) {
  __shared__ unsigned short tile[32][66];
  const int tx = threadIdx.x & 31, ty = threadIdx.x >> 5;
#pragma unroll
  for (int i = 0; i < 8; ++i)
    tile[tx][ty + 8 * i] = f2bf(W[(size_t)(k0 + ty + 8 * i) * N + n0 + tx]);
  __syncthreads();
#pragma unroll
  for (int j = 0; j < 4; ++j) {
    const int nn = ty + 8 * j;
    const unsigned pk = *(const unsigned*)&tile[nn][2 * tx];
    *(unsigned*)&out[(size_t)(n0 + nn) * K + k0 + 2 * tx] = pk;
  }
}

__global__ __launch_bounds__(256) void k_transpose4(
    const float* __restrict__ W0, const float* __restrict__ W1,
    const float* __restrict__ W2, const float* __restrict__ W3,
    unsigned short* __restrict__ WT) {
  const float* W = (blockIdx.z == 0) ? W0 : (blockIdx.z == 1) ? W1
                   : (blockIdx.z == 2) ? W2 : W3;
  unsigned short* out = WT + (size_t)blockIdx.z * C_ * C_;
  transpose_tile(W, out, C_, C_, blockIdx.x * 64, blockIdx.y * 32);
}

__global__ __launch_bounds__(256) void k_transpose1(
    const float* __restrict__ W, unsigned short* __restrict__ WT, int K, int N) {
  transpose_tile(W, WT, K, N, blockIdx.x * 64, blockIdx.y * 32);
}

// ---------- LayerNorm over C=2048 (f32 in, bf16 out + f32 last-row out) ----------
__global__ __launch_bounds__(256) void k_layernorm(
    const float* __restrict__ x, const float* __restrict__ g,
    const float* __restrict__ beta, unsigned short* __restrict__ y,
    float* __restrict__ last_out) {
  const int row = blockIdx.x;
  const int t = row & (T_ - 1);
  const int bi = row >> 11;
  const float* xr = x + (size_t)row * C_;
  const int base = threadIdx.x * 8;
  float lv[8];
  {
    float4 a = *(const float4*)(xr + base);
    float4 b = *(const float4*)(xr + base + 4);
    lv[0]=a.x; lv[1]=a.y; lv[2]=a.z; lv[3]=a.w; lv[4]=b.x; lv[5]=b.y; lv[6]=b.z; lv[7]=b.w;
  }
  float s = 0.f, q = 0.f;
#pragma unroll
  for (int j = 0; j < 8; ++j) { s += lv[j]; q += lv[j] * lv[j]; }
#pragma unroll
  for (int o = 32; o > 0; o >>= 1) { s += __shfl_down(s, o); q += __shfl_down(q, o); }
  __shared__ float rs[4], rq[4];
  if ((threadIdx.x & 63) == 0) { rs[threadIdx.x >> 6] = s; rq[threadIdx.x >> 6] = q; }
  __syncthreads();
  s = rs[0] + rs[1] + rs[2] + rs[3];
  q = rq[0] + rq[1] + rq[2] + rq[3];
  const float mean = s * (1.f / C_);
  const float var = q * (1.f / C_) - mean * mean;
  const float inv = 1.f / sqrtf(var + 1e-5f);
  float ov[8];
  unsigned short o8[8];
#pragma unroll
  for (int j = 0; j < 8; ++j) {
    ov[j] = (lv[j] - mean) * inv * g[base + j] + beta[base + j];
    o8[j] = f2bf(ov[j]);
  }
  *(uint4*)(y + (size_t)row * C_ + base) = *(uint4*)o8;
  if (last_out != nullptr && t == T_ - 1) {
    float* lp = last_out + (size_t)bi * C_ + base;
    *(float4*)lp = make_float4(ov[0], ov[1], ov[2], ov[3]);
    *(float4*)(lp + 4) = make_float4(ov[4], ov[5], ov[6], ov[7]);
  }
}

// ---------- token-shift mix (attention: 3 outputs), bf16 in/out ----------
__global__ __launch_bounds__(256) void k_mix3(
    const unsigned short* __restrict__ x1, const float* __restrict__ shift,
    const float* __restrict__ tmk, const float* __restrict__ tmv,
    const float* __restrict__ tmr,
    unsigned short* __restrict__ xk, unsigned short* __restrict__ xv,
    unsigned short* __restrict__ xr) {
  const int row = blockIdx.x;
  const int t = row & (T_ - 1);
  const int bi = row >> 11;
  const int c0 = threadIdx.x * 8;
  const size_t o = (size_t)row * C_ + c0;
  unsigned short cur8[8];
  *(uint4*)cur8 = *(const uint4*)(x1 + o);
  float pv[8];
  if (t == 0) {
    const float* sp = shift + (size_t)bi * C_ + c0;
#pragma unroll
    for (int j = 0; j < 8; ++j) pv[j] = sp[j];
  } else {
    unsigned short p8[8];
    *(uint4*)p8 = *(const uint4*)(x1 + o - C_);
#pragma unroll
    for (int j = 0; j < 8; ++j) pv[j] = b2f(p8[j]);
  }
  unsigned short ok[8], ov[8], orr[8];
#pragma unroll
  for (int j = 0; j < 8; ++j) {
    const float a = b2f(cur8[j]), p = pv[j];
    const float mk = tmk[c0 + j], mv = tmv[c0 + j], mr = tmr[c0 + j];
    ok[j]  = f2bf(a * mk + p * (1.f - mk));
    ov[j]  = f2bf(a * mv + p * (1.f - mv));
    orr[j] = f2bf(a * mr + p * (1.f - mr));
  }
  *(uint4*)(xk + o) = *(uint4*)ok;
  *(uint4*)(xv + o) = *(uint4*)ov;
  *(uint4*)(xr + o) = *(uint4*)orr;
}

// ---------- token-shift mix (ffn: 2 outputs) ----------
__global__ __launch_bounds__(256) void k_mix2(
    const unsigned short* __restrict__ x2, const float* __restrict__ shift,
    const float* __restrict__ fmk, const float* __restrict__ fmr,
    unsigned short* __restrict__ xk2, unsigned short* __restrict__ xr2) {
  const int row = blockIdx.x;
  const int t = row & (T_ - 1);
  const int bi = row >> 11;
  const int c0 = threadIdx.x * 8;
  const size_t o = (size_t)row * C_ + c0;
  unsigned short cur8[8];
  *(uint4*)cur8 = *(const uint4*)(x2 + o);
  float pv[8];
  if (t == 0) {
    const float* sp = shift + (size_t)bi * C_ + c0;
#pragma unroll
    for (int j = 0; j < 8; ++j) pv[j] = sp[j];
  } else {
    unsigned short p8[8];
    *(uint4*)p8 = *(const uint4*)(x2 + o - C_);
#pragma unroll
    for (int j = 0; j < 8; ++j) pv[j] = b2f(p8[j]);
  }
  unsigned short ok[8], orr[8];
#pragma unroll
  for (int j = 0; j < 8; ++j) {
    const float a = b2f(cur8[j]), p = pv[j];
    const float mk = fmk[c0 + j], mr = fmr[c0 + j];
    ok[j]  = f2bf(a * mk + p * (1.f - mk));
    orr[j] = f2bf(a * mr + p * (1.f - mr));
  }
  *(uint4*)(xk2 + o) = *(uint4*)ok;
  *(uint4*)(xr2 + o) = *(uint4*)orr;
}

// ---------- WKV block-local chunked scan, fused with sigmoid(r)*y -> sry bf16 ----
__global__ __launch_bounds__(256) void k_wkv_sry(
    const float* __restrict__ kk, const float* __restrict__ vv,
    const unsigned short* __restrict__ rr,
    const float* __restrict__ td, const float* __restrict__ tf,
    const float* __restrict__ st, unsigned short* __restrict__ sry,
    float* __restrict__ out_state) {
  __shared__ float sA[TCH][CHB], sB[TCH][CHB], sP[TCH][CHB];
  const int blk = blockIdx.x;
  const int bi = blk >> 7;
  const int tx = threadIdx.x & 15;
  const int ty = threadIdx.x >> 4;
  const int c = ((blk & 127) * CHB) + tx;
  const float w = -expf(td[c]);
  const float u = tf[c];
  const size_t base = (size_t)bi * T_ * C_ + (size_t)ty * LC2 * C_ + c;
  const float* kp = kk + base;
  const float* vp = vv + base;
  float aa = 0.f, bb = 0.f, pp = -1e38f;
#pragma unroll 8
  for (int i = 0; i < LC2; ++i) {
    const float kt = kp[(size_t)i * C_], vt = vp[(size_t)i * C_];
    const float ww2 = pp + w;
    const float p2 = fmaxf(ww2, kt);
    const float e1b = expf(ww2 - p2), e2b = expf(kt - p2);
    aa = e1b * aa + e2b * vt;
    bb = e1b * bb + e2b;
    pp = p2;
  }
  sA[ty][tx] = aa; sB[ty][tx] = bb; sP[ty][tx] = pp;
  __syncthreads();
  if (ty == 0) {
    const float* s0 = st + (size_t)bi * 3 * C_;
    float ca = s0[c], cb = s0[C_ + c], cp = s0[2 * C_ + c];
    const float wL = w * (float)LC2;
#pragma unroll
    for (int j = 0; j < TCH; ++j) {
      const float a2 = sA[j][tx], b2 = sB[j][tx], p2 = sP[j][tx];
      sA[j][tx] = ca; sB[j][tx] = cb; sP[j][tx] = cp;   // exclusive start
      const float pd = cp + wL;
      const float pm = fmaxf(pd, p2);
      const float e1 = expf(pd - pm), e2 = expf(p2 - pm);
      ca = e1 * ca + e2 * a2;
      cb = e1 * cb + e2 * b2;
      cp = pm;
    }
  }
  __syncthreads();
  aa = sA[ty][tx]; bb = sB[ty][tx]; pp = sP[ty][tx];
  const unsigned short* rp = rr + base;
  unsigned short* sp2 = sry + base;
#pragma unroll 4
  for (int i = 0; i < LC2; ++i) {
    const float kt = kp[(size_t)i * C_], vt = vp[(size_t)i * C_];
    const float ww = u + kt;
    const float p = fmaxf(pp, ww);
    const float e1 = expf(pp - p), e2 = expf(ww - p);
    const float yv = (e1 * aa + e2 * vt) / (e1 * bb + e2);
    const float rv = b2f(rp[(size_t)i * C_]);
    const float sg = 1.f / (1.f + expf(-rv));
    sp2[(size_t)i * C_] = f2bf(sg * yv);
    const float ww2 = pp + w;
    const float p2 = fmaxf(ww2, kt);
    const float e1b = expf(ww2 - p2), e2b = expf(kt - p2);
    aa = e1b * aa + e2b * vt;
    bb = e1b * bb + e2b;
    pp = p2;
  }
  if (ty == TCH - 1) {
    float* ob = out_state + (size_t)bi * 3 * C_;
    ob[c] = aa; ob[C_ + c] = bb; ob[2 * C_ + c] = pp;
  }
}

// ---------- bf16 MFMA GEMM: 128x256 tile, BK=64, 8 waves, single-barrier tiles --
// EPI 0: f32; 1: bf16(relu^2); 2: f32(aux1+acc); 3: f32(aux1+sig(acc)*aux2f32);
// 4: bf16 plain; 5: f32(aux1 + sig(acc)*(b2f(aux2bf)+b2f(aux3bf)))
template <int EPI, int SWZ>
__global__ __launch_bounds__(512, 1) void k_gemm8(
    const unsigned short* __restrict__ A, const unsigned short* __restrict__ BT,
    int K, int Nn, void* __restrict__ out,
    const float* __restrict__ aux1, const void* __restrict__ aux2,
    const void* __restrict__ aux3) {
  __shared__ unsigned short lds[73728];
  const int tid = threadIdx.x;
  const int lane = tid & 63;
  const int wid = tid >> 6;
  int mBase, nBase;
  if (SWZ) {
    const int gx = gridDim.x, gy = gridDim.y;
    const int wg = blockIdx.y * gx + blockIdx.x;
    const int per = (gx * gy) >> 3;
    const int p = 31 - __clz(per);
    const int nr = 1 << ((p - 1) >> 1);
    const int mr = per / nr;
    if ((gx % nr) == 0 && (gy % mr) == 0) {
      const int gxr = gx / nr;
      const int xcd = wg & 7, idx = wg >> 3;
      const int rr = xcd / gxr, rc = xcd % gxr;
      mBase = (rr * mr + idx / nr) * 128;
      nBase = (rc * nr + idx % nr) * 256;
    } else {
      int w2 = (wg & 7) * per + (wg >> 3);
      mBase = (w2 / gx) * 128;
      nBase = (w2 % gx) * 256;
    }
  } else {
    mBase = blockIdx.y * 128;
    nBase = blockIdx.x * 256;
  }
  const int wr = (wid >> 2) * 64;
  const int wc = (wid & 3) * 64;
  const int r16 = lane & 15, kq = lane >> 4;
  const int lrow = lane >> 3;
  const int lslot = (lane & 7) ^ lrow;
  const int xsw = r16 & 7;
  f32x4 acc[4][4] = {};

  const unsigned short* gA0 = A  + (size_t)(mBase + 0   + wid * 8 + lrow) * K + lslot * 8;
  const unsigned short* gA1 = A  + (size_t)(mBase + 64  + wid * 8 + lrow) * K + lslot * 8;
  const unsigned short* gB0 = BT + (size_t)(nBase + 0   + wid * 8 + lrow) * K + lslot * 8;
  const unsigned short* gB1 = BT + (size_t)(nBase + 64  + wid * 8 + lrow) * K + lslot * 8;
  const unsigned short* gB2 = BT + (size_t)(nBase + 128 + wid * 8 + lrow) * K + lslot * 8;
  const unsigned short* gB3 = BT + (size_t)(nBase + 192 + wid * 8 + lrow) * K + lslot * 8;
  const int wof = wid * 512;
  int aoff[4][2], boff[4][2];
#pragma unroll
  for (int m = 0; m < 4; ++m)
#pragma unroll
    for (int s = 0; s < 2; ++s)
      aoff[m][s] = (wr + m * 16 + r16) * 64 + (((s * 4 + kq) ^ xsw) * 8);
#pragma unroll
  for (int n = 0; n < 4; ++n)
#pragma unroll
    for (int s = 0; s < 2; ++s)
      boff[n][s] = 8192 + (wc + n * 16 + r16) * 64 + (((s * 4 + kq) ^ xsw) * 8);

  const int nt = K >> 6;
  gload16(gA0, &lds[0 + wof]);
  gload16(gA1, &lds[4096 + wof]);
  gload16(gB0, &lds[8192 + wof]);
  gload16(gB1, &lds[12288 + wof]);
  gload16(gB2, &lds[16384 + wof]);
  gload16(gB3, &lds[20480 + wof]);
  gload16(gA0 + 64, &lds[24576 + 0 + wof]);
  gload16(gA1 + 64, &lds[24576 + 4096 + wof]);
  gload16(gB0 + 64, &lds[24576 + 8192 + wof]);
  gload16(gB1 + 64, &lds[24576 + 12288 + wof]);
  gload16(gB2 + 64, &lds[24576 + 16384 + wof]);
  gload16(gB3 + 64, &lds[24576 + 20480 + wof]);
  asm volatile("s_waitcnt vmcnt(6)" ::: "memory");
  asm volatile("s_barrier" ::: "memory");

  int cb = 0;
  for (int t = 0; t < nt; ++t) {
    const int nb = (cb >= 1) ? cb - 1 : 2;
    const int ca = cb * 24576;
    const int nba = nb * 24576;
    const int kb2 = (t + 2) << 6;
    const bool pf = (t + 2) < nt;
    if (pf) {
      gload16(gA0 + kb2, &lds[nba + 0 + wof]);
      gload16(gA1 + kb2, &lds[nba + 4096 + wof]);
      gload16(gB0 + kb2, &lds[nba + 8192 + wof]);
      gload16(gB1 + kb2, &lds[nba + 12288 + wof]);
      gload16(gB2 + kb2, &lds[nba + 16384 + wof]);
      gload16(gB3 + kb2, &lds[nba + 20480 + wof]);
    }
    bf16x8 af[4][2], bq[4][2];
#pragma unroll
    for (int m = 0; m < 4; ++m)
#pragma unroll
      for (int s = 0; s < 2; ++s)
        af[m][s] = *(const bf16x8*)&lds[ca + aoff[m][s]];
#pragma unroll
    for (int n = 0; n < 4; ++n)
#pragma unroll
      for (int s = 0; s < 2; ++s)
        bq[n][s] = *(const bf16x8*)&lds[ca + boff[n][s]];
    __builtin_amdgcn_s_setprio(1);
#pragma unroll
    for (int m = 0; m < 4; ++m)
#pragma unroll
      for (int n = 0; n < 4; ++n)
#pragma unroll
        for (int s = 0; s < 2; ++s)
          acc[m][n] = __builtin_amdgcn_mfma_f32_16x16x32_bf16(
              af[m][s], bq[n][s], acc[m][n], 0, 0, 0);
    __builtin_amdgcn_s_setprio(0);
    if (pf) {
      asm volatile("s_waitcnt vmcnt(6)" ::: "memory");
    } else if (t + 1 < nt) {
      asm volatile("s_waitcnt vmcnt(0)" ::: "memory");
    }
    asm volatile("s_barrier" ::: "memory");
    cb = (cb == 2) ? 0 : cb + 1;
  }

  const int c0 = kq * 4;
#pragma unroll
  for (int m = 0; m < 4; ++m) {
#pragma unroll
    for (int n = 0; n < 4; ++n) {
      const int col = nBase + wc + n * 16 + r16;
#pragma unroll
      for (int e = 0; e < 4; ++e) {
        const int rowg = mBase + wr + m * 16 + c0 + e;
        const size_t idx = (size_t)rowg * Nn + col;
        const float va = acc[m][n][e];
        if (EPI == 0) {
          ((float*)out)[idx] = va;
        } else if (EPI == 1) {
          const float t = va > 0.f ? va : 0.f;
          ((unsigned short*)out)[idx] = f2bf(t * t);
        } else if (EPI == 2) {
          ((float*)out)[idx] = aux1[idx] + va;
        } else if (EPI == 3) {
          const float s = 1.f / (1.f + expf(-va));
          ((float*)out)[idx] = aux1[idx] + s * ((const float*)aux2)[idx];
        } else if (EPI == 5) {
          const float s = 1.f / (1.f + expf(-va));
          const float kvv = b2f(((const unsigned short*)aux2)[idx]) +
                            b2f(((const unsigned short*)aux3)[idx]);
          ((float*)out)[idx] = aux1[idx] + s * kvv;
        } else {
          ((unsigned short*)out)[idx] = f2bf(va);
        }
      }
    }
  }
}

// ---------- shared 256x256 GEMM core (round-17 pipeline): computes acc ----------
__device__ __forceinline__ void gemm256_core(
    const unsigned short* __restrict__ A, const unsigned short* __restrict__ BT,
    int K, int Klen, int Koff, int mBase, int nBase,
    unsigned short* lds, f32x4 (&acc)[8][4]) {
  const int lane = threadIdx.x & 63;
  const int wid = threadIdx.x >> 6;
  const int wr = (wid >> 2) * 128;
  const int wc = (wid & 3) * 64;
  const int r16 = lane & 15, kq = lane >> 4;
  const int lrow = lane >> 3;
  const int lslot = (lane & 7) ^ lrow;
  const int xsw = r16 & 7;
  const unsigned short* gA[4];
  const unsigned short* gB[4];
#pragma unroll
  for (int j = 0; j < 4; ++j) {
    gA[j] = A  + (size_t)(mBase + j * 64 + wid * 8 + lrow) * K + Koff + lslot * 8;
    gB[j] = BT + (size_t)(nBase + j * 64 + wid * 8 + lrow) * K + Koff + lslot * 8;
  }
  const int wof = wid * 512;
  const int nt = Klen >> 6;
#pragma unroll
  for (int j = 0; j < 4; ++j) {
    gload16(gA[j], &lds[j * 4096 + wof]);
    gload16(gB[j], &lds[16384 + j * 4096 + wof]);
  }
  asm volatile("s_waitcnt vmcnt(0)" ::: "memory");
  asm volatile("s_barrier" ::: "memory");

  for (int t = 0; t < nt; ++t) {
    const int ca = (t & 1) * 32768;
    const int nba = ((t + 1) & 1) * 32768;
    const int kb1 = (t + 1) << 6;
    const bool pf = (t + 1) < nt;
    if (pf) {
#pragma unroll
      for (int j = 0; j < 4; ++j) {
        gload16(gA[j] + kb1, &lds[nba + j * 4096 + wof]);
        gload16(gB[j] + kb1, &lds[nba + 16384 + j * 4096 + wof]);
      }
    }
    bf16x8 bq[4][2];
#pragma unroll
    for (int n = 0; n < 4; ++n)
#pragma unroll
      for (int s = 0; s < 2; ++s)
        bq[n][s] = *(const bf16x8*)&lds[ca + 16384 + (wc + n * 16 + r16) * 64 +
                                        (((s * 4 + kq) ^ xsw) * 8)];
#pragma unroll
    for (int qm = 0; qm < 2; ++qm) {
      bf16x8 af[4][2];
#pragma unroll
      for (int m = 0; m < 4; ++m)
#pragma unroll
        for (int s = 0; s < 2; ++s)
          af[m][s] = *(const bf16x8*)&lds[ca + (wr + (qm * 4 + m) * 16 + r16) * 64 +
                                          (((s * 4 + kq) ^ xsw) * 8)];
      __builtin_amdgcn_s_setprio(1);
#pragma unroll
      for (int m = 0; m < 4; ++m)
#pragma unroll
        for (int n = 0; n < 4; ++n)
#pragma unroll
          for (int s = 0; s < 2; ++s)
            acc[qm * 4 + m][n] = __builtin_amdgcn_mfma_f32_16x16x32_bf16(
                af[m][s], bq[n][s], acc[qm * 4 + m][n], 0, 0, 0);
      __builtin_amdgcn_s_setprio(0);
    }
    if (pf) asm volatile("s_waitcnt vmcnt(0)" ::: "memory");
    asm volatile("s_barrier" ::: "memory");
  }
}

__device__ __forceinline__ void swz256(int gx, int gy, int& mBase, int& nBase) {
  const int wg = blockIdx.y * gx + blockIdx.x;
  const int per = (gx * gy) >> 3;
  const int p = 31 - __clz(per);
  const int nr = 1 << (p >> 1);
  const int mr = per / nr;
  if ((gx % nr) == 0 && (gy % mr) == 0) {
    const int gxr = gx / nr;
    const int xcd = wg & 7, idx = wg >> 3;
    const int rr = xcd / gxr, rc = xcd % gxr;
    mBase = (rr * mr + idx / nr) * 256;
    nBase = (rc * nr + idx % nr) * 256;
  } else {
    int w2 = (wg & 7) * per + (wg >> 3);
    mBase = (w2 / gx) * 256;
    nBase = (w2 % gx) * 256;
  }
}

// ---------- 256x256 GEMM (Fk / split-K kv): EPI 1 bf16(relu^2), 4 bf16 ----------
template <int EPI>
__global__ __launch_bounds__(512, 1) void k_gemm256(
    const unsigned short* __restrict__ A, const unsigned short* __restrict__ BT,
    int K, int Klen, int Nn, void* __restrict__ out, size_t outStride) {
  __shared__ unsigned short lds[65536];
  int mBase, nBase;
  swz256(gridDim.x, gridDim.y, mBase, nBase);
  void* outz = (char*)out + (size_t)blockIdx.z * outStride;
  f32x4 acc[8][4] = {};
  gemm256_core(A, BT, K, Klen, blockIdx.z * Klen, mBase, nBase, lds, acc);
  const int lane = threadIdx.x & 63;
  const int wid = threadIdx.x >> 6;
  const int wr = (wid >> 2) * 128, wc = (wid & 3) * 64;
  const int r16 = lane & 15, kq = lane >> 4;
  const int c0 = kq * 4;
#pragma unroll
  for (int m = 0; m < 8; ++m) {
#pragma unroll
    for (int n = 0; n < 4; ++n) {
      const int col = nBase + wc + n * 16 + r16;
#pragma unroll
      for (int e = 0; e < 4; ++e) {
        const int rowg = mBase + wr + m * 16 + c0 + e;
        const size_t idx = (size_t)rowg * Nn + col;
        const float va = acc[m][n][e];
        if (EPI == 1) {
          const float t = va > 0.f ? va : 0.f;
          ((unsigned short*)outz)[idx] = f2bf(t * t);
        } else {
          ((unsigned short*)outz)[idx] = f2bf(va);
        }
      }
    }
  }
}

extern "C" void kernel_launch(void* const* d_in, const int* in_sizes, int n_in,
                              void* d_out, int out_size, void* d_ws, size_t ws_size,
                              hipStream_t stream) {
  const float* x          = (const float*)d_in[0];
  const float* att_shift  = (const float*)d_in[1];
  const float* wkv_state  = (const float*)d_in[2];
  const float* ffn_shift  = (const float*)d_in[3];
  const float* ln1_g = (const float*)d_in[4];
  const float* ln1_b = (const float*)d_in[5];
  const float* ln2_g = (const float*)d_in[6];
  const float* ln2_b = (const float*)d_in[7];
  const float* tmk = (const float*)d_in[8];
  const float* tmv = (const float*)d_in[9];
  const float* tmr = (const float*)d_in[10];
  const float* time_decay = (const float*)d_in[11];
  const float* time_first = (const float*)d_in[12];
  const float* Wk = (const float*)d_in[13];
  const float* Wv = (const float*)d_in[14];
  const float* Wr = (const float*)d_in[15];
  const float* Wo = (const float*)d_in[16];
  const float* fmk = (const float*)d_in[17];
  const float* fmr = (const float*)d_in[18];
  const float* Fk = (const float*)d_in[19];
  const float* Fr = (const float*)d_in[20];
  const float* Fv = (const float*)d_in[21];

  // ---- 176 MiB workspace, strictly sequential reuse, zero in-flight overlap ----
  const size_t MB = 1ull << 20;
  char* ws = (char*)d_ws;
  if (ws_size < 176 * MB) return;

  unsigned short* Wslot = (unsigned short*)(ws);             //   0.. 32 weight slots
  float*          kBuf  = (float*)(ws + 32 * MB);            //  32.. 64 k f32
  float*          vBuf  = (float*)(ws + 64 * MB);            //  64.. 96 v f32
  float*          yBuf  = (float*)(ws + 96 * MB);            //  96..128 x_att f32
  unsigned short* h1    = (unsigned short*)(ws + 128 * MB);  // 128..144 x1 -> r -> x2
  unsigned short* h2    = (unsigned short*)(ws + 144 * MB);  // 144..160 xk -> sry -> xk2
  unsigned short* h3    = (unsigned short*)(ws + 160 * MB);  // 160..176 xv -> xr2
  unsigned short* xrT   = (unsigned short*)kBuf;             // xr bf16, before k exists
  unsigned short* kf    = (unsigned short*)kBuf;             // 64 MiB: 32..96 (k,v dead)
  unsigned short* kvp   = (unsigned short*)h1;               // 2x16 MiB bf16 partials
  // 4 transposed C_xC_ weight slots inside Wslot (8 MiB each)
  unsigned short* sWr = Wslot + 0 * (size_t)C_ * C_;
  unsigned short* sWk = Wslot + 1 * (size_t)C_ * C_;
  unsigned short* sWv = Wslot + 2 * (size_t)C_ * C_;
  unsigned short* sWo = Wslot + 3 * (size_t)C_ * C_;

  // ---- f32 outputs, concatenated in reference return order ----
  float* outb    = (float*)d_out;
  float* x1_last = outb + (size_t)M_ * C_;        // [B,C]
  float* wkv_out = x1_last + (size_t)B_ * C_;     // [B,3,C]
  float* x2_last = wkv_out + (size_t)B_ * 3 * C_; // [B,C]

  const dim3 gC8(C_ / 256, M_ / 128);       // 8 x 32 = 256 WGs
  const dim3 gF256(F_ / 256, M_ / 256);     // 32 x 16 = 512 WGs
  const dim3 gKV(C_ / 256, M_ / 256, 2);    // split-K kv

  // ---- attention path ----
  k_transpose4<<<dim3(C_ / 64, C_ / 32, 4), 256, 0, stream>>>(Wr, Wk, Wv, Wo, Wslot);
  k_layernorm<<<M_, 256, 0, stream>>>(x, ln1_g, ln1_b, h1, x1_last);           // x1 -> h1
  k_mix3<<<M_, 256, 0, stream>>>(h1, att_shift, tmk, tmv, tmr, h2, h3, xrT);   // xk,xv,xr
  k_gemm8<4,1><<<gC8, 512, 0, stream>>>(xrT, sWr, C_, C_, h1, nullptr, nullptr, nullptr); // r
  k_gemm8<0,1><<<gC8, 512, 0, stream>>>(h2, sWk, C_, C_, kBuf, nullptr, nullptr, nullptr); // k
  k_gemm8<0,1><<<gC8, 512, 0, stream>>>(h3, sWv, C_, C_, vBuf, nullptr, nullptr, nullptr); // v
  k_wkv_sry<<<dim3(BC_ / CHB), 256, 0, stream>>>(kBuf, vBuf, h1, time_decay, time_first,
                                                 wkv_state, h2, wkv_out);      // sry -> h2
  k_gemm8<2,1><<<gC8, 512, 0, stream>>>(h2, sWo, C_, C_, yBuf, x, nullptr, nullptr); // x_att

  // ---- ffn path ----
  k_layernorm<<<M_, 256, 0, stream>>>(yBuf, ln2_g, ln2_b, h1, x2_last);         // x2 -> h1
  k_mix2<<<M_, 256, 0, stream>>>(h1, ffn_shift, fmk, fmr, h2, h3);              // xk2,xr2
  k_transpose1<<<dim3(C_ / 64, F_ / 32), 256, 0, stream>>>(Fk, Wslot, C_, F_);
  k_gemm256<1><<<gF256, 512, 0, stream>>>(h2, Wslot, C_, C_, F_, kf, 0);        // kf bf16
  k_transpose1<<<dim3(F_ / 64, C_ / 32), 256, 0, stream>>>(Fv, Wslot, F_, C_);
  k_gemm256<4><<<gKV, 512, 0, stream>>>(kf, Wslot, F_, F_ / 2, C_, kvp, 16 * MB); // kv partials
  k_transpose1<<<dim3(C_ / 64, C_ / 32), 256, 0, stream>>>(Fr, Wslot, C_, C_);
  k_gemm8<5,1><<<gC8, 512, 0, stream>>>(h3, Wslot, C_, C_, d_out, yBuf,
                                        kvp, kvp + 8 * (size_t)MB);             // final f32
}